// Round 1
// baseline (660.444 us; speedup 1.0000x reference)
//
#include <hip/hip_runtime.h>
#include <stdint.h>

typedef unsigned short u16;
typedef unsigned int u32;
typedef float f32x4 __attribute__((ext_vector_type(4)));
typedef short short8 __attribute__((ext_vector_type(8)));

#define NBAT 32
#define NSEQ 4096
#define ND 256
#define NSLOT 7

// ---------------- helpers ----------------
__device__ __forceinline__ u32 bf16rne(float f){
  u32 u = __float_as_uint(f);
  u = u + 0x7FFFu + ((u >> 16) & 1u);
  return u >> 16;
}
__device__ __forceinline__ u32 packbf(float a, float b){
  return (bf16rne(a) & 0xFFFFu) | (bf16rne(b) << 16);
}
__device__ __forceinline__ float bflo(u32 u){ return __uint_as_float(u << 16); }
__device__ __forceinline__ float bfhi(u32 u){ return __uint_as_float(u & 0xFFFF0000u); }

__device__ __forceinline__ void gld16(void* lds, const void* g){
  __builtin_amdgcn_global_load_lds(
      (const __attribute__((address_space(1))) u32*)g,
      (__attribute__((address_space(3))) u32*)lds, 16, 0, 0);
}

__device__ __forceinline__ void softmax7(const float* z, float* p){
  float m = fmaxf(fmaxf(fmaxf(z[0], z[1]), fmaxf(z[2], z[3])),
                  fmaxf(fmaxf(z[4], z[5]), z[6]));
  float sum = 0.f;
#pragma unroll
  for (int s = 0; s < 7; ++s){ p[s] = exp2f(z[s] - m); sum += p[s]; }
  float r = 1.f / sum;
#pragma unroll
  for (int s = 0; s < 7; ++s) p[s] = fmaf(p[s], r, 1e-8f);
}

// ---------------- prep: Wkv bf16 concat, bias concat, slots init ----------------
__global__ __launch_bounds__(256) void k_prep(
    const float* __restrict__ wk, const float* __restrict__ wv,
    const float* __restrict__ bk, const float* __restrict__ bv,
    const float* __restrict__ mu, const float* __restrict__ sig,
    const float* __restrict__ noise,
    u16* __restrict__ Wkv, float* __restrict__ biaskv, float* __restrict__ slots){
  const int bid = blockIdx.x, t = threadIdx.x;
  if (bid < 512){
    const float* src = (bid < 256) ? (wk + (size_t)bid*256) : (wv + (size_t)(bid-256)*256);
    Wkv[(size_t)bid*256 + t] = (u16)bf16rne(src[t]);
  } else if (bid == 512){
    biaskv[t] = bk[t];
    biaskv[256 + t] = bv[t];
  } else {
    int r = bid - 513; // 0..223  (b*7+s)
    float sp = logf(1.f + expf(sig[t]));   // softplus
    slots[(size_t)r*256 + t] = mu[t] + sp * noise[(size_t)r*256 + t];
  }
}

// ---------------- K1: LayerNorm(inputs) -> x bf16, one wave per row ----------------
__global__ __launch_bounds__(256) void k_ln_in(
    const float* __restrict__ x, const float* __restrict__ g, const float* __restrict__ b,
    u16* __restrict__ xo){
  const int row = blockIdx.x*4 + (threadIdx.x >> 6);
  const int lane = threadIdx.x & 63;
  const f32x4 v = *(const f32x4*)(x + (size_t)row*ND + lane*4);
  float s  = v[0]+v[1]+v[2]+v[3];
  float s2 = v[0]*v[0]+v[1]*v[1]+v[2]*v[2]+v[3]*v[3];
#pragma unroll
  for (int m = 1; m < 64; m <<= 1){ s += __shfl_xor(s, m); s2 += __shfl_xor(s2, m); }
  const float mean = s * (1.f/256.f);
  const float var  = s2 * (1.f/256.f) - mean*mean;
  const float rstd = rsqrtf(var + 1e-5f);
  const f32x4 gg = *(const f32x4*)(g + lane*4);
  const f32x4 bb = *(const f32x4*)(b + lane*4);
  float y0 = (v[0]-mean)*rstd*gg[0] + bb[0];
  float y1 = (v[1]-mean)*rstd*gg[1] + bb[1];
  float y2 = (v[2]-mean)*rstd*gg[2] + bb[2];
  float y3 = (v[3]-mean)*rstd*gg[3] + bb[3];
  uint2 o; o.x = packbf(y0, y1); o.y = packbf(y2, y3);
  *(uint2*)(xo + (size_t)row*ND + lane*4) = o;
}

// ---------------- K2: kv = x @ Wkv^T + bias  (MFMA bf16, 128x128 tile, BK=64) ----------------
__global__ __launch_bounds__(256) void k_gemm_kv(
    const u16* __restrict__ X, const u16* __restrict__ W,
    const float* __restrict__ biaskv, u16* __restrict__ kv){
  __shared__ __align__(16) u16 At[128*64];
  __shared__ __align__(16) u16 Bt[128*64];
  const int nb = blockIdx.x, mb = blockIdx.y;
  const int tid = threadIdx.x, w = tid >> 6, lane = tid & 63;
  const int wm = w >> 1, wn = w & 1;
  f32x4 acc[4][4];
#pragma unroll
  for (int a = 0; a < 4; ++a)
#pragma unroll
    for (int c = 0; c < 4; ++c) acc[a][c] = (f32x4){0.f,0.f,0.f,0.f};

  const int cl = lane & 7;
  for (int kt = 0; kt < 4; ++kt){
#pragma unroll
    for (int i = 0; i < 4; ++i){
      int R = w*32 + i*8 + (lane >> 3);
      int c = cl ^ (R & 7);                 // source pre-swizzle (st_16B XOR)
      gld16(&At[(w*32 + i*8)*64], X + ((size_t)(mb*128 + R))*256 + kt*64 + c*8);
      gld16(&Bt[(w*32 + i*8)*64], W + ((size_t)(nb*128 + R))*256 + kt*64 + c*8);
    }
    __syncthreads();
#pragma unroll
    for (int kk = 0; kk < 2; ++kk){
      short8 xf[4], wf[4];
#pragma unroll
      for (int xi = 0; xi < 4; ++xi){
        int r = wm*64 + xi*16 + (lane & 15);
        int ch = (kk*4 + (lane >> 4)) ^ (r & 7);
        xf[xi] = *(const short8*)&At[r*64 + ch*8];
      }
#pragma unroll
      for (int wi = 0; wi < 4; ++wi){
        int r = wn*64 + wi*16 + (lane & 15);
        int ch = (kk*4 + (lane >> 4)) ^ (r & 7);
        wf[wi] = *(const short8*)&Bt[r*64 + ch*8];
      }
#pragma unroll
      for (int xi = 0; xi < 4; ++xi)
#pragma unroll
        for (int wi = 0; wi < 4; ++wi)
          // D[i][j], i = W-row (output col), j = X-row (output row)
          // -> each lane holds 4 CONSECUTIVE output cols => packed bf16 stores
          acc[xi][wi] = __builtin_amdgcn_mfma_f32_16x16x32_bf16(wf[wi], xf[xi], acc[xi][wi], 0, 0, 0);
    }
    __syncthreads();
  }
  // epilogue: + bias, cvt bf16, 8B stores
  f32x4 bias[4];
#pragma unroll
  for (int wi = 0; wi < 4; ++wi)
    bias[wi] = *(const f32x4*)(biaskv + nb*128 + wn*64 + wi*16 + (lane >> 4)*4);
#pragma unroll
  for (int xi = 0; xi < 4; ++xi){
    size_t m = (size_t)mb*128 + wm*64 + xi*16 + (lane & 15);
    u16* dst = kv + m*512 + nb*128 + wn*64 + (lane >> 4)*4;
#pragma unroll
    for (int wi = 0; wi < 4; ++wi){
      f32x4 c = acc[xi][wi];
      uint2 o;
      o.x = packbf(c[0] + bias[wi][0], c[1] + bias[wi][1]);
      o.y = packbf(c[2] + bias[wi][2], c[3] + bias[wi][3]);
      *(uint2*)(dst + wi*16) = o;
    }
  }
}

// ---------------- K3: q = LN(slots) @ wq^T + bq, pre-scaled by log2(e)/16 ----------------
__global__ __launch_bounds__(256) void k_qproj(
    const float* __restrict__ slots, const float* __restrict__ g, const float* __restrict__ b,
    const float* __restrict__ wq, const float* __restrict__ bq, float* __restrict__ qeff){
  __shared__ __align__(16) float lnv[256];
  __shared__ float red[8];
  const int bs = blockIdx.x, t = threadIdx.x;
  float x = slots[(size_t)bs*256 + t];
  float s = x, s2 = x*x;
#pragma unroll
  for (int m = 1; m < 64; m <<= 1){ s += __shfl_xor(s, m); s2 += __shfl_xor(s2, m); }
  if ((t & 63) == 0){ red[t >> 6] = s; red[4 + (t >> 6)] = s2; }
  __syncthreads();
  float ssum = red[0]+red[1]+red[2]+red[3];
  float qsum = red[4]+red[5]+red[6]+red[7];
  float mean = ssum*(1.f/256.f);
  float var  = qsum*(1.f/256.f) - mean*mean;
  float rstd = rsqrtf(var + 1e-5f);
  lnv[t] = (x - mean)*rstd*g[t] + b[t];
  __syncthreads();
  const float* wrow = wq + (size_t)t*256;
  f32x4 a = {0.f,0.f,0.f,0.f};
  for (int k = 0; k < 256; k += 4)
    a += *(const f32x4*)&lnv[k] * *(const f32x4*)(wrow + k);
  float r = a[0]+a[1]+a[2]+a[3] + bq[t];
  qeff[(size_t)bs*256 + t] = r * 0.09016844f; // log2(e)/16
}

// ---------------- K4: fused logits -> softmax(S) -> partial (p'@v, sum p') ----------------
__global__ __launch_bounds__(256) void k_attn(
    const u16* __restrict__ kv, const float* __restrict__ qeff,
    float* __restrict__ attn_out, float* __restrict__ pacc, float* __restrict__ pw){
  __shared__ __align__(16) float accbuf[4][7][256];
  __shared__ float wsbuf[4][7];
  const int chunk = blockIdx.x, b = blockIdx.y;
  const int tid = threadIdx.x, w = tid >> 6, lane = tid & 63, hi = lane >> 5, lo = lane & 31;
  float qr[7][8];
  {
    const float* qb = qeff + (size_t)b*(NSLOT*256) + lo*8;
#pragma unroll
    for (int s = 0; s < 7; ++s){
      f32x4 q0 = *(const f32x4*)(qb + s*256);
      f32x4 q1 = *(const f32x4*)(qb + s*256 + 4);
      qr[s][0]=q0[0]; qr[s][1]=q0[1]; qr[s][2]=q0[2]; qr[s][3]=q0[3];
      qr[s][4]=q1[0]; qr[s][5]=q1[1]; qr[s][6]=q1[2]; qr[s][7]=q1[3];
    }
  }
  float acc[7][4]; float wsm[7];
#pragma unroll
  for (int s = 0; s < 7; ++s){ acc[s][0]=acc[s][1]=acc[s][2]=acc[s][3]=0.f; wsm[s]=0.f; }

  const size_t bbase = (size_t)b*NSEQ;
  for (int it = 0; it < 16; ++it){
    const int nr = chunk*128 + it*8 + w*2;
    const size_t rowm = (bbase + nr + hi)*512;        // my row
    const size_t rowo = (bbase + nr + (1 - hi))*512;  // partner row
    uint4 k4 = *(const uint4*)(kv + rowm + lo*8);
    float kf[8];
    kf[0]=bflo(k4.x); kf[1]=bfhi(k4.x); kf[2]=bflo(k4.y); kf[3]=bfhi(k4.y);
    kf[4]=bflo(k4.z); kf[5]=bfhi(k4.z); kf[6]=bflo(k4.w); kf[7]=bfhi(k4.w);
    float z[7];
#pragma unroll
    for (int s = 0; s < 7; ++s){
      float d0 = fmaf(qr[s][0],kf[0], fmaf(qr[s][1],kf[1], fmaf(qr[s][2],kf[2], qr[s][3]*kf[3])));
      float d1 = fmaf(qr[s][4],kf[4], fmaf(qr[s][5],kf[5], fmaf(qr[s][6],kf[6], qr[s][7]*kf[7])));
      z[s] = d0 + d1;
    }
#pragma unroll
    for (int m = 1; m < 32; m <<= 1){
#pragma unroll
      for (int s = 0; s < 7; ++s) z[s] += __shfl_xor(z[s], m);
    }
    float zo[7];
#pragma unroll
    for (int s = 0; s < 7; ++s) zo[s] = __shfl_xor(z[s], 32);
    float pm[7], po[7];
    softmax7(z, pm);
    softmax7(zo, po);
    // write unnormalized p' (normalized later by k_norm)
    float sel = pm[0];
    sel = (lo==1)?pm[1]:sel; sel = (lo==2)?pm[2]:sel; sel = (lo==3)?pm[3]:sel;
    sel = (lo==4)?pm[4]:sel; sel = (lo==5)?pm[5]:sel; sel = (lo==6)?pm[6]:sel;
    if (lo < 7) attn_out[(bbase + nr + hi)*7 + lo] = sel;
    // v accumulation: lane owns d = lane*4..lane*4+3, accumulates BOTH rows
    uint2 va = *(const uint2*)(kv + rowm + 256 + (size_t)lane*4);
    uint2 vb = *(const uint2*)(kv + rowo + 256 + (size_t)lane*4);
    float vm0=bflo(va.x), vm1=bfhi(va.x), vm2=bflo(va.y), vm3=bfhi(va.y);
    float vo0=bflo(vb.x), vo1=bfhi(vb.x), vo2=bflo(vb.y), vo3=bfhi(vb.y);
#pragma unroll
    for (int s = 0; s < 7; ++s){
      acc[s][0] = fmaf(pm[s], vm0, fmaf(po[s], vo0, acc[s][0]));
      acc[s][1] = fmaf(pm[s], vm1, fmaf(po[s], vo1, acc[s][1]));
      acc[s][2] = fmaf(pm[s], vm2, fmaf(po[s], vo2, acc[s][2]));
      acc[s][3] = fmaf(pm[s], vm3, fmaf(po[s], vo3, acc[s][3]));
      wsm[s] += pm[s] + po[s];
    }
  }
#pragma unroll
  for (int s = 0; s < 7; ++s)
    *(f32x4*)&accbuf[w][s][lane*4] = (f32x4){acc[s][0], acc[s][1], acc[s][2], acc[s][3]};
  if (lane == 0){
#pragma unroll
    for (int s = 0; s < 7; ++s) wsbuf[w][s] = wsm[s];
  }
  __syncthreads();
#pragma unroll
  for (int s = 0; s < 7; ++s){
    float sum = accbuf[0][s][tid] + accbuf[1][s][tid] + accbuf[2][s][tid] + accbuf[3][s][tid];
    pacc[((size_t)chunk*NBAT + b)*(NSLOT*256) + s*256 + tid] = sum;
  }
  if (tid < 7)
    pw[((size_t)chunk*NBAT + b)*NSLOT + tid] =
        wsbuf[0][tid] + wsbuf[1][tid] + wsbuf[2][tid] + wsbuf[3][tid];
}

// ---------------- K5: reduce partials -> updates; GRU; LN; MLP; slots update ----------------
__global__ __launch_bounds__(768) void k_slot(
    const float* __restrict__ pacc, const float* __restrict__ pw,
    float* __restrict__ slots,
    const float* __restrict__ w_ih, const float* __restrict__ b_ih,
    const float* __restrict__ w_hh, const float* __restrict__ b_hh,
    const float* __restrict__ gm, const float* __restrict__ bm,
    const float* __restrict__ w1, const float* __restrict__ b1,
    const float* __restrict__ w2, const float* __restrict__ b2,
    float* __restrict__ wsum_tot, float* __restrict__ out_slots, int last){
  __shared__ __align__(16) float updk[256], spv[256], lnv[256], hbuf[512];
  __shared__ float gib[768], ghb[768], snew[256];
  __shared__ float pwb[32];
  __shared__ float reds[12], redq[12];
  const int bs = blockIdx.x, t = threadIdx.x;
  if (t < 32) pwb[t] = pw[(size_t)t*224 + bs];
  __syncthreads();
  float wst = 0.f;
#pragma unroll
  for (int c = 0; c < 32; ++c) wst += pwb[c];
  const float inv = 1.f / wst;
  if (t == 0) wsum_tot[bs] = wst;
  if (t < 256){
    float u = 0.f;
    for (int c = 0; c < 32; ++c) u += pacc[(size_t)c*57344 + (size_t)bs*256 + t];
    updk[t] = u * inv;
    spv[t] = slots[(size_t)bs*256 + t];
  }
  __syncthreads();
  {
    const float* wi_ = w_ih + (size_t)t*256;
    const float* wh_ = w_hh + (size_t)t*256;
    f32x4 ai = {0.f,0.f,0.f,0.f}, ah = {0.f,0.f,0.f,0.f};
    for (int k = 0; k < 256; k += 4){
      f32x4 u4 = *(const f32x4*)&updk[k];
      f32x4 s4 = *(const f32x4*)&spv[k];
      ai += u4 * *(const f32x4*)(wi_ + k);
      ah += s4 * *(const f32x4*)(wh_ + k);
    }
    gib[t] = ai[0]+ai[1]+ai[2]+ai[3] + b_ih[t];
    ghb[t] = ah[0]+ah[1]+ah[2]+ah[3] + b_hh[t];
  }
  __syncthreads();
  float sp = 0.f;
  if (t < 256){
    float rr = 1.f/(1.f + __expf(-(gib[t] + ghb[t])));
    float zz = 1.f/(1.f + __expf(-(gib[256+t] + ghb[256+t])));
    float xx = gib[512+t] + rr*ghb[512+t];
    xx = fminf(fmaxf(xx, -15.f), 15.f);
    float e2 = __expf(2.f*xx);
    float nn = (e2 - 1.f)/(e2 + 1.f);
    sp = (1.f - zz)*nn + zz*spv[t];
    snew[t] = sp;
  }
  __syncthreads();
  float rs = sp, rq = sp*sp;
#pragma unroll
  for (int m = 1; m < 64; m <<= 1){ rs += __shfl_xor(rs, m); rq += __shfl_xor(rq, m); }
  if ((t & 63) == 0){ reds[t >> 6] = rs; redq[t >> 6] = rq; }
  __syncthreads();
  float ssum = 0.f, qsum = 0.f;
#pragma unroll
  for (int i = 0; i < 12; ++i){ ssum += reds[i]; qsum += redq[i]; }
  const float mean = ssum*(1.f/256.f);
  const float var  = qsum*(1.f/256.f) - mean*mean;
  const float rstd = rsqrtf(var + 1e-5f);
  if (t < 256) lnv[t] = (sp - mean)*rstd*gm[t] + bm[t];
  __syncthreads();
  if (t < 512){
    const float* wr = w1 + (size_t)t*256;
    f32x4 a = {0.f,0.f,0.f,0.f};
    for (int k = 0; k < 256; k += 4)
      a += *(const f32x4*)&lnv[k] * *(const f32x4*)(wr + k);
    hbuf[t] = fmaxf(a[0]+a[1]+a[2]+a[3] + b1[t], 0.f);
  }
  __syncthreads();
  if (t < 256){
    const float* wr = w2 + (size_t)t*512;
    f32x4 a = {0.f,0.f,0.f,0.f};
    for (int k = 0; k < 512; k += 4)
      a += *(const f32x4*)&hbuf[k] * *(const f32x4*)(wr + k);
    float o = snew[t] + a[0]+a[1]+a[2]+a[3] + b2[t];
    slots[(size_t)bs*256 + t] = o;
    if (last) out_slots[(size_t)bs*256 + t] = o;
  }
}

// ---------------- K6: attn /= sum over n ----------------
__global__ __launch_bounds__(256) void k_norm(
    float* __restrict__ attn, const float* __restrict__ wsum_tot){
  size_t i = (size_t)blockIdx.x*256 + threadIdx.x;
  int s = (int)(i % 7);
  int b = (int)(i / (NSEQ*7));
  attn[i] = attn[i] / wsum_tot[b*7 + s];
}

// ---------------- launch ----------------
extern "C" void kernel_launch(void* const* d_in, const int* in_sizes, int n_in,
                              void* d_out, int out_size, void* d_ws, size_t ws_size,
                              hipStream_t stream){
  (void)in_sizes; (void)n_in; (void)out_size; (void)ws_size;
  const float* inputs  = (const float*)d_in[0];
  const float* noise   = (const float*)d_in[1];
  const float* ln_in_g = (const float*)d_in[2];
  const float* ln_in_b = (const float*)d_in[3];
  const float* ln_sl_g = (const float*)d_in[4];
  const float* ln_sl_b = (const float*)d_in[5];
  const float* ln_ml_g = (const float*)d_in[6];
  const float* ln_ml_b = (const float*)d_in[7];
  const float* mu      = (const float*)d_in[8];
  const float* sig     = (const float*)d_in[9];
  const float* wq      = (const float*)d_in[10];
  const float* bq      = (const float*)d_in[11];
  const float* wk      = (const float*)d_in[12];
  const float* bk      = (const float*)d_in[13];
  const float* wv      = (const float*)d_in[14];
  const float* bv      = (const float*)d_in[15];
  const float* w_ih    = (const float*)d_in[16];
  const float* b_ih    = (const float*)d_in[17];
  const float* w_hh    = (const float*)d_in[18];
  const float* b_hh    = (const float*)d_in[19];
  const float* w1      = (const float*)d_in[20];
  const float* b1      = (const float*)d_in[21];
  const float* w2      = (const float*)d_in[22];
  const float* b2      = (const float*)d_in[23];

  char* ws = (char*)d_ws;
  u16*   x_bf   = (u16*)(ws);                         // 67108864 B
  u16*   kv     = (u16*)(ws + 67108864);              // 134217728 B
  float* pacc   = (float*)(ws + 201326592);           // 7340032 B
  u16*   Wkv    = (u16*)(ws + 208666624);             // 262144 B
  float* qeff   = (float*)(ws + 208928768);           // 229376 B
  float* slots  = (float*)(ws + 209158144);           // 229376 B
  float* pw     = (float*)(ws + 209387520);           // 28672 B
  float* biaskv = (float*)(ws + 209416192);           // 2048 B
  float* wsum   = (float*)(ws + 209418240);           // 896 B

  float* out_slots = (float*)d_out;
  float* attn = (float*)d_out + 57344;

  k_prep<<<737, 256, 0, stream>>>(wk, wv, bk, bv, mu, sig, noise, Wkv, biaskv, slots);
  k_ln_in<<<32768, 256, 0, stream>>>(inputs, ln_in_g, ln_in_b, x_bf);
  k_gemm_kv<<<dim3(4, 1024), 256, 0, stream>>>(x_bf, Wkv, biaskv, kv);
  for (int i = 0; i < 3; ++i){
    k_qproj<<<224, 256, 0, stream>>>(slots, ln_sl_g, ln_sl_b, wq, bq, qeff);
    k_attn<<<dim3(32, 32), 256, 0, stream>>>(kv, qeff, attn, pacc, pw);
    k_slot<<<224, 768, 0, stream>>>(pacc, pw, slots, w_ih, b_ih, w_hh, b_hh,
                                    ln_ml_g, ln_ml_b, w1, b1, w2, b2,
                                    wsum, out_slots, (i == 2) ? 1 : 0);
  }
  k_norm<<<3584, 256, 0, stream>>>(attn, wsum);
}